// Round 10
// baseline (521.762 us; speedup 1.0000x reference)
//
#include <hip/hip_runtime.h>
#include <hip/hip_bf16.h>
#include <math.h>

// ---- problem constants ----
#define DIMC 192
#define NTOK 343
#define NHEADS 6
#define HD 32
#define NN 117649           // NTOK*NTOK
#define MLP 768
#define MTOT 43904
#define QSCALE 0.17677669529663687f

// ---- ws fixed regions ----
// biasQ[h][88][344][4] bf16 = 6*88*344*4*2 = 1,453,056 B
#define WS_WGT    1453056
#define OFF_QKVW  0
#define OFF_PROJW 110592
#define OFF_FC1W  147456
#define OFF_FC2W  294912
#define NWGT      442368
#define WS_CHUNK  2337792             // WS_WGT + 884,736

typedef __attribute__((ext_vector_type(8))) short bf16x8;
typedef __attribute__((ext_vector_type(4))) float f32x4;

typedef const unsigned __attribute__((address_space(1)))* gas1_t;
typedef unsigned __attribute__((address_space(3)))* las3_t;
__device__ __forceinline__ void gld16(const void* g, void* l) {
    __builtin_amdgcn_global_load_lds((gas1_t)g, (las3_t)l, 16, 0, 0);
}

__device__ __forceinline__ float b2f(__hip_bfloat16 v) { return __bfloat162float(v); }
__device__ __forceinline__ __hip_bfloat16 f2b(float v) { return __float2bfloat16(v); }
__device__ __forceinline__ unsigned short bfu(float v) {
    __hip_bfloat16 b = f2b(v);
    return *(unsigned short*)&b;
}

__device__ __forceinline__ float2 bfp2(unsigned u) {
    union { unsigned i; float f; } a, b;
    a.i = u << 16;
    b.i = u & 0xffff0000u;
    return make_float2(a.f, b.f);
}

// (global window, token-in-window) -> linear token index in x (handles cyclic shift)
__device__ __forceinline__ int win_to_tok(int w, int n) {
    int bb = w >> 6, widx = w & 63;
    int wd = widx >> 4, wh = (widx >> 2) & 3, ww = widx & 3;
    int sd = n / 49, r = n - sd * 49;
    int sh = r / 7, sw = r - sh * 7;
    int gd = wd * 7 + sd + 3; if (gd >= 28) gd -= 28;
    int gh = wh * 7 + sh + 3; if (gh >= 28) gh -= 28;
    int gw = ww * 7 + sw + 3; if (gw >= 28) gw -= 28;
    return bb * 21952 + gd * 784 + gh * 28 + gw;
}

// Swin shift-mask region id for (window widx 0..63, token n)
__device__ __forceinline__ int region_of(int widx, int n) {
    int wd = widx >> 4, wh = (widx >> 2) & 3, ww = widx & 3;
    int sd = n / 49, rr = n - sd * 49;
    int sh = rr / 7, sw = rr - sh * 7;
    int cd = wd * 7 + sd, ch = wh * 7 + sh, cw = ww * 7 + sw;
    int dsl = (cd < 21) ? 0 : ((cd < 25) ? 1 : 2);
    int hsl = (ch < 21) ? 0 : ((ch < 25) ? 1 : 2);
    int wsl = (cw < 21) ? 0 : ((cw < 25) ? 1 : 2);
    return dsl * 9 + hsl * 3 + wsl;
}

// ---------------- rel-position bias, A-frag-friendly: biasQ[h][m>>2][q][m&3] bf16 ----------------
__global__ __launch_bounds__(256) void bias_kernel(
    const int* __restrict__ rel, const float* __restrict__ table,
    __hip_bfloat16* __restrict__ biasQ) {
    int idx = blockIdx.x * 256 + threadIdx.x;   // idx = m*343 + q
    if (idx >= NN) return;
    int m = idx / NTOK, q = idx - m * NTOK;
    int ri = rel[q * NTOK + m];
    #pragma unroll
    for (int h = 0; h < NHEADS; h++)
        biasQ[(((size_t)h * 88 + (m >> 2)) * 344 + q) * 4 + (m & 3)] = f2b(table[ri * NHEADS + h]);
}

// ---------------- weights fp32 -> bf16 ----------------
__global__ __launch_bounds__(256) void wconv_kernel(
    const float* __restrict__ qkv_w, const float* __restrict__ proj_w,
    const float* __restrict__ fc1_w, const float* __restrict__ fc2_w,
    __hip_bfloat16* __restrict__ Wb) {
    int i = blockIdx.x * 256 + threadIdx.x;
    if (i >= NWGT) return;
    float v;
    if      (i < OFF_PROJW) v = qkv_w[i - OFF_QKVW];
    else if (i < OFF_FC1W)  v = proj_w[i - OFF_PROJW];
    else if (i < OFF_FC2W)  v = fc1_w[i - OFF_FC1W];
    else                    v = fc2_w[i - OFF_FC2W];
    Wb[i] = f2b(v);
}

// ---------------- LN1 + shift + window partition (bf16 out) ----------------
__global__ __launch_bounds__(256) void ln1_kernel(
    const float* __restrict__ x, const float* __restrict__ g,
    const float* __restrict__ bt, __hip_bfloat16* __restrict__ wins,
    int w0, int Mrows) {
    int t = blockIdx.x * 4 + (threadIdx.x >> 6);
    if (t >= Mrows) return;
    int lane = threadIdx.x & 63;
    int wl = t / NTOK, n = t - wl * NTOK;
    int tok = win_to_tok(w0 + wl, n);
    const float* xp = x + (size_t)tok * DIMC;
    float v0 = xp[lane], v1 = xp[lane + 64], v2 = xp[lane + 128];
    float s = v0 + v1 + v2, s2 = v0 * v0 + v1 * v1 + v2 * v2;
    #pragma unroll
    for (int m = 32; m >= 1; m >>= 1) { s += __shfl_xor(s, m, 64); s2 += __shfl_xor(s2, m, 64); }
    float mean = s * (1.f / 192.f);
    float var = s2 * (1.f / 192.f) - mean * mean;
    float r = rsqrtf(var + 1e-5f);
    __hip_bfloat16* op = wins + (size_t)t * DIMC;
    op[lane]       = f2b((v0 - mean) * r * g[lane]       + bt[lane]);
    op[lane + 64]  = f2b((v1 - mean) * r * g[lane + 64]  + bt[lane + 64]);
    op[lane + 128] = f2b((v2 - mean) * r * g[lane + 128] + bt[lane + 128]);
}

// ---------------- LN2 (fp32 x2 in from d_out, bf16 out) ----------------
__global__ __launch_bounds__(256) void ln2_kernel(
    const float* __restrict__ x2, const float* __restrict__ g,
    const float* __restrict__ bt, __hip_bfloat16* __restrict__ y, int r0g) {
    int t = blockIdx.x * 4 + (threadIdx.x >> 6);
    int lane = threadIdx.x & 63;
    const float* xp = x2 + (size_t)(r0g + t) * DIMC;
    float v0 = xp[lane], v1 = xp[lane + 64], v2 = xp[lane + 128];
    float s = v0 + v1 + v2, s2 = v0 * v0 + v1 * v1 + v2 * v2;
    #pragma unroll
    for (int m = 32; m >= 1; m >>= 1) { s += __shfl_xor(s, m, 64); s2 += __shfl_xor(s2, m, 64); }
    float mean = s * (1.f / 192.f);
    float var = s2 * (1.f / 192.f) - mean * mean;
    float r = rsqrtf(var + 1e-5f);
    __hip_bfloat16* op = y + (size_t)t * DIMC;
    op[lane]       = f2b((v0 - mean) * r * g[lane]       + bt[lane]);
    op[lane + 64]  = f2b((v1 - mean) * r * g[lane + 64]  + bt[lane + 64]);
    op[lane + 128] = f2b((v2 - mean) * r * g[lane + 128] + bt[lane + 128]);
}

// ---------------- MFMA GEMM with global_load_lds staging ----------------
template <int EPI>
__global__ __launch_bounds__(256) void gemm_kernel(
    const __hip_bfloat16* __restrict__ A, const __hip_bfloat16* __restrict__ Bw,
    const float* __restrict__ bias, int K, int Mrows, int w0, int r0g,
    const float* __restrict__ shortcut, float* __restrict__ xout,
    void* __restrict__ out_p) {
    __shared__ __align__(16) __hip_bfloat16 As[256 * 32];
    __shared__ __align__(16) __hip_bfloat16 Bs[64 * 32];
    int tid = threadIdx.x;
    int wave = tid >> 6, lane = tid & 63;
    int quad = lane >> 4, r = lane & 15;
    int row0 = blockIdx.y * 256, col0 = blockIdx.x * 64;
    int lrow = lane >> 2, lcol = (lane & 3) * 8;
    f32x4 acc[4][4];
    #pragma unroll
    for (int mi = 0; mi < 4; mi++)
        #pragma unroll
        for (int ni = 0; ni < 4; ni++) acc[mi][ni] = (f32x4){0.f, 0.f, 0.f, 0.f};
    for (int k0 = 0; k0 < K; k0 += 32) {
        // async stage A (wave's own 64 rows) and B (wave's 16 rows): lane i -> ldsbase + i*16B
        #pragma unroll
        for (int inst = 0; inst < 4; inst++) {
            int rowl = wave * 64 + inst * 16 + lrow;
            int ar = row0 + rowl; if (ar >= Mrows) ar = Mrows - 1;
            gld16(A + (size_t)ar * K + k0 + lcol, &As[(wave * 64 + inst * 16) * 32]);
        }
        {
            int rowb = wave * 16 + lrow;
            gld16(Bw + (size_t)(col0 + rowb) * K + k0 + lcol, &Bs[(wave * 16) * 32]);
        }
        __syncthreads();
        bf16x8 af[4], bf[4];
        #pragma unroll
        for (int mi = 0; mi < 4; mi++)
            af[mi] = *(const bf16x8*)&As[(wave * 64 + mi * 16 + r) * 32 + quad * 8];
        #pragma unroll
        for (int ni = 0; ni < 4; ni++)
            bf[ni] = *(const bf16x8*)&Bs[(ni * 16 + r) * 32 + quad * 8];
        #pragma unroll
        for (int mi = 0; mi < 4; mi++)
            #pragma unroll
            for (int ni = 0; ni < 4; ni++)
                acc[mi][ni] = __builtin_amdgcn_mfma_f32_16x16x32_bf16(af[mi], bf[ni], acc[mi][ni], 0, 0, 0);
        __syncthreads();
    }
    #pragma unroll
    for (int mi = 0; mi < 4; mi++) {
        #pragma unroll
        for (int i = 0; i < 4; i++) {
            int rloc = wave * 64 + mi * 16 + quad * 4 + i;
            int rr = row0 + rloc;
            if (rr >= Mrows) continue;
            #pragma unroll
            for (int ni = 0; ni < 4; ni++) {
                int c = col0 + ni * 16 + r;
                float v = acc[mi][ni][i] + bias[c];
                if (EPI == 0) {
                    int wl = rr / NTOK, n = rr - wl * NTOK;
                    int t = c / DIMC, rem = c - t * DIMC;
                    int hh = rem >> 5, d = rem & 31;
                    if (t == 0) v *= QSCALE;
                    ((__hip_bfloat16*)out_p)[((((size_t)wl * NHEADS + hh) * 3 + t) * NTOK + n) * HD + d] = f2b(v);
                } else if (EPI == 1) {
                    int wl = rr / NTOK, n = rr - wl * NTOK;
                    size_t tok = (size_t)win_to_tok(w0 + wl, n);
                    xout[tok * DIMC + c] = v + shortcut[tok * DIMC + c];
                } else if (EPI == 2) {
                    float gel = 0.5f * v * (1.0f + erff(v * 0.70710678118654752f));
                    ((__hip_bfloat16*)out_p)[(size_t)rr * MLP + c] = f2b(gel);
                } else {
                    size_t gi = (size_t)(r0g + rr) * DIMC + c;
                    xout[gi] += v;
                }
            }
        }
    }
}

// ---------------- MFMA attention v3 ----------------
// grid (W*NHEADS, 2): block = (window, head, q-half). 4 waves, each 2-3 q-tiles.
// Single-pass softmax (scores provably bounded -> no max subtraction), unnormalized
// P -> PV, normalize output by 1/l. K staged zero-padded in LDS (no clamps).
__global__ __launch_bounds__(256) void attn_kernel(
    const __hip_bfloat16* __restrict__ qkv, const __hip_bfloat16* __restrict__ biasQ,
    __hip_bfloat16* __restrict__ out, int w0) {
    int wl = blockIdx.x / NHEADS, h = blockIdx.x - wl * NHEADS;
    int wm = (w0 + wl) & 63;
    int y = blockIdx.y;
    __shared__ __align__(16) __hip_bfloat16 Ks[352 * 32];   // 22,528 B (rows 343..351 zero)
    __shared__ __align__(16) unsigned VtU[32 * 180];        // 23,040 B: V^T [d][m], stride 360 el
    __shared__ unsigned char regS[352];
    const __hip_bfloat16* base = qkv + ((size_t)(wl * NHEADS + h) * 3) * NTOK * HD;
    const __hip_bfloat16* Kp = base + NTOK * HD;
    const unsigned* Vp = (const unsigned*)(base + 2 * NTOK * HD);   // [m][dpair]
    int tid = threadIdx.x;
    for (int i = tid; i < 352; i += 256) regS[i] = (i < NTOK) ? (unsigned char)region_of(wm, i) : 255;
    for (int u = tid; u < 1408; u += 256) {
        uint4 v = (u < 1372) ? ((const uint4*)Kp)[u] : make_uint4(0, 0, 0, 0);
        ((uint4*)Ks)[u] = v;
    }
    for (int u = tid; u < 176 * 16; u += 256) {
        int m2 = u >> 4, dp = u & 15;
        unsigned a = 0, b = 0;
        if (m2 <= 170)      { a = Vp[(2 * m2) * 16 + dp]; b = Vp[(2 * m2 + 1) * 16 + dp]; }
        else if (m2 == 171) { a = Vp[342 * 16 + dp]; }
        VtU[(2 * dp) * 180 + m2]     = (a & 0xffffu) | (b << 16);
        VtU[(2 * dp + 1) * 180 + m2] = (a >> 16) | (b & 0xffff0000u);
    }
    __syncthreads();
    int wave = tid >> 6, lane = tid & 63;
    int quad = lane >> 4, r = lane & 15;
    const __hip_bfloat16* vt = (const __hip_bfloat16*)&VtU[0];
    for (int qt = y * 11 + wave; qt < (y + 1) * 11; qt += 4) {
        int q0 = qt * 16;
        int qc = q0 + r; if (qc > 342) qc = 342;
        bf16x8 qf = *(const bf16x8*)(base + (size_t)qc * HD + quad * 8);
        int rq = regS[qc];
        float l = 0.f;
        int Pn[22][2];
        #pragma unroll
        for (int mt = 0; mt < 22; mt++) {
            bf16x8 kf = *(const bf16x8*)(Ks + (mt * 16 + r) * 32 + quad * 8);
            f32x4 c = {0.f, 0.f, 0.f, 0.f};
            c = __builtin_amdgcn_mfma_f32_16x16x32_bf16(kf, qf, c, 0, 0, 0);
            uint2 bu = *(const uint2*)(biasQ + (((size_t)h * 88 + mt * 4 + quad) * 344 + qc) * 4);
            float2 blo = bfp2(bu.x), bhi = bfp2(bu.y);
            float bv[4] = {blo.x, blo.y, bhi.x, bhi.y};
            float p[4];
            #pragma unroll
            for (int i = 0; i < 4; i++) {
                int m = mt * 16 + quad * 4 + i;
                float msk = (regS[m] == rq) ? 0.f : -100.f;
                p[i] = __expf(c[i] + bv[i] + msk);
                l += p[i];
            }
            Pn[mt][0] = (int)((unsigned)bfu(p[0]) | ((unsigned)bfu(p[1]) << 16));
            Pn[mt][1] = (int)((unsigned)bfu(p[2]) | ((unsigned)bfu(p[3]) << 16));
        }
        l += __shfl_xor(l, 16, 64);
        l += __shfl_xor(l, 32, 64);
        float rl = 1.f / l;
        // ---- O = P·V: A-frag built by cross-quad shuffles ----
        f32x4 o0 = {0.f, 0.f, 0.f, 0.f}, o1 = {0.f, 0.f, 0.f, 0.f};
        bool hiQuad = (quad >= 2);
        int srcBase = (quad & 1) * 32 + r;
        #pragma unroll
        for (int ch = 0; ch < 11; ch++) {
            unsigned afu[4];
            #pragma unroll
            for (int k = 0; k < 4; k++) {
                int src = srcBase + (k >> 1) * 16;
                int lo = __shfl(Pn[2 * ch][k & 1], src, 64);
                int hi = __shfl(Pn[2 * ch + 1][k & 1], src, 64);
                afu[k] = (unsigned)(hiQuad ? hi : lo);
            }
            bf16x8 pf = *(bf16x8*)afu;
            bf16x8 v0 = *(const bf16x8*)(vt + (size_t)r * 360 + ch * 32 + quad * 8);
            bf16x8 v1 = *(const bf16x8*)(vt + (size_t)(r + 16) * 360 + ch * 32 + quad * 8);
            o0 = __builtin_amdgcn_mfma_f32_16x16x32_bf16(pf, v0, o0, 0, 0, 0);
            o1 = __builtin_amdgcn_mfma_f32_16x16x32_bf16(pf, v1, o1, 0, 0, 0);
        }
        float rli[4];
        #pragma unroll
        for (int i = 0; i < 4; i++) rli[i] = __shfl(rl, quad * 4 + i, 64);
        #pragma unroll
        for (int i = 0; i < 4; i++) {
            int q = q0 + quad * 4 + i;
            if (q < NTOK) {
                __hip_bfloat16* orow = out + ((size_t)wl * NTOK + q) * DIMC + h * HD;
                orow[r] = f2b(o0[i] * rli[i]);
                orow[r + 16] = f2b(o1[i] * rli[i]);
            }
        }
    }
}

extern "C" void kernel_launch(void* const* d_in, const int* in_sizes, int n_in,
                              void* d_out, int out_size, void* d_ws, size_t ws_size,
                              hipStream_t stream) {
    const float* x      = (const float*)d_in[0];
    const int*   relidx = (const int*)d_in[2];
    const float* table  = (const float*)d_in[3];
    const float* n1g    = (const float*)d_in[4];
    const float* n1b    = (const float*)d_in[5];
    const float* qkv_w  = (const float*)d_in[6];
    const float* qkv_b  = (const float*)d_in[7];
    const float* proj_w = (const float*)d_in[8];
    const float* proj_b = (const float*)d_in[9];
    const float* n2g    = (const float*)d_in[10];
    const float* n2b    = (const float*)d_in[11];
    const float* fc1_w  = (const float*)d_in[12];
    const float* fc1_b  = (const float*)d_in[13];
    const float* fc2_w  = (const float*)d_in[14];
    const float* fc2_b  = (const float*)d_in[15];

    char* ws = (char*)d_ws;
    __hip_bfloat16* biasQ = (__hip_bfloat16*)ws;
    __hip_bfloat16* Wb    = (__hip_bfloat16*)(ws + WS_WGT);
    float* out = (float*)d_out;          // fp32 output == residual stream x2

    // ---- ws-adaptive chunks ----
    int W = 1;
    {
        const int cand[8] = {128, 64, 32, 16, 8, 4, 2, 1};
        for (int i = 0; i < 8; i++)
            if ((size_t)WS_CHUNK + (size_t)cand[i] * 526848 <= ws_size) { W = cand[i]; break; }
    }
    int R = 64;
    {
        const int cand[9] = {43904, 21952, 10976, 6272, 3136, 896, 448, 128, 64};
        for (int i = 0; i < 9; i++)
            if ((size_t)WS_CHUNK + (size_t)cand[i] * 1920 <= ws_size) { R = cand[i]; break; }
    }
    __hip_bfloat16* R0  = (__hip_bfloat16*)(ws + WS_CHUNK);
    __hip_bfloat16* QKV = (__hip_bfloat16*)(ws + WS_CHUNK + (size_t)W * 131712);
    __hip_bfloat16* Y   = (__hip_bfloat16*)(ws + WS_CHUNK);
    __hip_bfloat16* HID = (__hip_bfloat16*)(ws + WS_CHUNK + (size_t)R * 384);

    bias_kernel<<<(NN + 255) / 256, 256, 0, stream>>>(relidx, table, biasQ);
    wconv_kernel<<<(NWGT + 255) / 256, 256, 0, stream>>>(qkv_w, proj_w, fc1_w, fc2_w, Wb);

    // ---- attention path ----
    int mch = W * NTOK;
    int gy = (mch + 255) / 256;
    int gln = (mch + 3) / 4;
    for (int c = 0; c < 128 / W; c++) {
        int w0 = c * W;
        ln1_kernel<<<gln, 256, 0, stream>>>(x, n1g, n1b, R0, w0, mch);
        gemm_kernel<0><<<dim3(9, gy), 256, 0, stream>>>(
            R0, Wb + OFF_QKVW, qkv_b, DIMC, mch, w0, 0, nullptr, nullptr, QKV);
        attn_kernel<<<dim3(W * NHEADS, 2), 256, 0, stream>>>(QKV, biasQ, R0, w0);
        gemm_kernel<1><<<dim3(3, gy), 256, 0, stream>>>(
            R0, Wb + OFF_PROJW, proj_b, DIMC, mch, w0, 0, x, out, nullptr);
    }
    // ---- MLP path ----
    for (int m = 0; m < MTOT / R; m++) {
        int r0g = m * R;
        int gyr = (R + 255) / 256;
        ln2_kernel<<<R / 4, 256, 0, stream>>>(out, n2g, n2b, Y, r0g);
        gemm_kernel<2><<<dim3(12, gyr), 256, 0, stream>>>(
            Y, Wb + OFF_FC1W, fc1_b, DIMC, R, 0, 0, nullptr, nullptr, HID);
        gemm_kernel<3><<<dim3(3, gyr), 256, 0, stream>>>(
            HID, Wb + OFF_FC2W, fc2_b, MLP, R, 0, r0g, nullptr, out, nullptr);
    }
}